// Round 1
// baseline (3033.294 us; speedup 1.0000x reference)
//
#include <hip/hip_runtime.h>

#define J 27
#define D 512
#define H 8
#define DH 64
#define NLAYER 6
#define DFF 2048
#define NB 64
#define NP 2048
#define CAP 128
#define NCH 8
#define NEGF -1000000000.0f

__constant__ int c_parent[J] = {0,0,1,2,3,4,5,6,7,8,8,3,11,12,13,14,15,15,0,18,19,20,0,22,23,24,3};
__constant__ float c_scale[J] = {0.6f,0.6f,0.6f,0.6f,1.f,1.f,1.f,1.f,1.f,1.5f,1.5f,1.f,1.f,1.f,1.f,1.f,
                                 1.5f,1.5f,0.6f,1.f,1.5f,1.5f,0.6f,1.f,1.5f,1.5f,1.5f};

__device__ __forceinline__ float siluf(float x){ return x/(1.f+expf(-x)); }

// ---------- per (b,j): denom sum, rescue idx (argmin dist), allmask, active-bitmap marks ----------
__global__ void k_perj(const float* __restrict__ x_t, const float* __restrict__ pc,
                       float* __restrict__ denom_sum, int* __restrict__ rescue,
                       int* __restrict__ allm, unsigned int* __restrict__ bitmap){
  int bj = blockIdx.x; int b = bj / J, j = bj % J;
  int t = threadIdx.x;
  float x0 = x_t[(b*J+j)*3+0];
  float x1 = x_t[(b*J+j)*3+1];
  float x2 = x_t[(b*J+j)*3+2];
  float sx = x0*x0+x1*x1+x2*x2;
  float ar = c_scale[j]*0.1f;
  float sig = ar*0.5f;
  float twos2 = 2.f*sig*sig;
  float sum = 0.f, bmin = 3.4e38f; int bidx = NP; int any = 0;
  for (int n = t; n < NP; n += 256){
    const float* p = pc + ((size_t)b*NP + n)*6;
    float p0=p[0], p1=p[1], p2=p[2];
    float d2 = sx + (p0*p0+p1*p1+p2*p2) - 2.f*(x0*p0+x1*p1+x2*p2);
    float dist = sqrtf(fmaxf(d2, 0.f));
    sum += expf(-(dist*dist)/twos2);
    if (dist < bmin){ bmin = dist; bidx = n; }
    if (dist <= ar){ any = 1; atomicOr(&bitmap[b*(NP/32)+(n>>5)], 1u<<(n&31)); }
  }
  __shared__ float ssum[256]; __shared__ float smin[256];
  __shared__ int sidx[256]; __shared__ int sany[256];
  ssum[t]=sum; smin[t]=bmin; sidx[t]=bidx; sany[t]=any;
  __syncthreads();
  for (int s = 128; s > 0; s >>= 1){
    if (t < s){
      ssum[t] += ssum[t+s];
      if (smin[t+s] < smin[t] || (smin[t+s]==smin[t] && sidx[t+s] < sidx[t])){ smin[t]=smin[t+s]; sidx[t]=sidx[t+s]; }
      sany[t] |= sany[t+s];
    }
    __syncthreads();
  }
  if (t == 0){
    denom_sum[bj] = ssum[0];
    rescue[bj] = sidx[0];
    allm[bj] = sany[0] ? 0 : 1;
    if (!sany[0]) atomicOr(&bitmap[b*(NP/32)+(sidx[0]>>5)], 1u<<(sidx[0]&31));
  }
}

// ---------- ordered compaction of active bitmap -> per-batch index list (1 wave / batch) ----------
__global__ void k_compact(const unsigned int* __restrict__ bitmap, int* __restrict__ act_idx,
                          int* __restrict__ act_cnt){
  int b = blockIdx.x; int t = threadIdx.x; // 64 threads = 1 wave
  unsigned int w = bitmap[b*(NP/32)+t];
  int c = __popc(w);
  int off = c;
  for (int s = 1; s < 64; s <<= 1){
    int v = __shfl_up(off, s);
    if (t >= s) off += v;
  }
  int total = __shfl(off, 63);
  off -= c; // exclusive
  int base = off;
  for (int bit = 0; bit < 32; ++bit){
    if (w & (1u<<bit)){
      if (base < CAP) act_idx[b*CAP+base] = t*32+bit;
      base++;
    }
  }
  if (t == 0) act_cnt[b] = total > CAP ? CAP : total;
}

__global__ void k_scan(const int* __restrict__ act_cnt, int* __restrict__ act_off,
                       int* __restrict__ act_total){
  if (threadIdx.x == 0){
    int s = 0;
    for (int b = 0; b < NB; ++b){ act_off[b] = s; s += act_cnt[b]; }
    act_total[0] = s;
  }
}

// ---------- G[b,ch,j,h] = sum_n dw[b,j,n] * silu(dop*w1[h]+b1[h])  (chunked) ----------
__global__ void k_gpart(const float* __restrict__ x_t, const float* __restrict__ pc,
                        const float* __restrict__ dop_w1, const float* __restrict__ dop_b1,
                        float* __restrict__ Gp){
  int b = blockIdx.x, ch = blockIdx.y; int t = threadIdx.x;
  __shared__ float sx[J*3];
  __shared__ float w1[64], b1[64];
  __shared__ float hid[64];
  __shared__ float dwrow[J];
  __shared__ float G[J*64];
  if (t < J*3) sx[t] = x_t[b*J*3 + t];
  if (t >= 96 && t < 160){ w1[t-96] = dop_w1[t-96]; b1[t-96] = dop_b1[t-96]; }
  for (int e = t; e < J*64; e += 256) G[e] = 0.f;
  __syncthreads();
  int n0 = ch * (NP/NCH);
  for (int n = n0; n < n0 + NP/NCH; ++n){
    if (t < 64){
      float dop = pc[((size_t)b*NP+n)*6+3];
      hid[t] = siluf(dop*w1[t]+b1[t]);
    } else if (t < 64+J){
      int j = t-64;
      float x0=sx[j*3], x1=sx[j*3+1], x2=sx[j*3+2];
      const float* p = pc + ((size_t)b*NP+n)*6;
      float p0=p[0], p1=p[1], p2=p[2];
      float d2 = (x0*x0+x1*x1+x2*x2) + (p0*p0+p1*p1+p2*p2) - 2.f*(x0*p0+x1*p1+x2*p2);
      float dist = sqrtf(fmaxf(d2, 0.f));
      float sig = c_scale[j]*0.05f;
      float twos2 = 2.f*sig*sig;
      dwrow[j] = expf(-(dist*dist)/twos2);
    }
    __syncthreads();
    for (int e = t; e < J*64; e += 256){ int j = e>>6, hh = e&63; G[e] += dwrow[j]*hid[hh]; }
    __syncthreads();
  }
  float* out = Gp + ((size_t)(b*NCH+ch))*J*64;
  for (int e = t; e < J*64; e += 256) out[e] = G[e];
}

// ---------- h_dop[b,j,:] = (G @ w2 + S*b2) / (S + 1e-6) ----------
__global__ void k_hdop2(const float* __restrict__ Gp, const float* __restrict__ dop_w2,
                        const float* __restrict__ dop_b2, const float* __restrict__ denom_sum,
                        float* __restrict__ h_dop){
  int bj = blockIdx.x; int b = bj/J, j = bj%J; int t = threadIdx.x; // 64
  __shared__ float G[64];
  float g = 0.f;
  for (int c = 0; c < NCH; ++c) g += Gp[((size_t)(b*NCH+c)*J + j)*64 + t];
  G[t] = g; __syncthreads();
  float S = denom_sum[bj];
  float inv = 1.f/(S + 1e-6f);
  float* out = h_dop + (size_t)bj*D;
  for (int u = 0; u < D/64; ++u){
    int d = u*64 + t;
    float acc = 0.f;
    for (int hh = 0; hh < 64; ++hh) acc += G[hh]*dop_w2[hh*D+d];
    out[d] = (acc + S*dop_b2[d]) * inv;
  }
}

// ---------- out[r,d] = in[r,0..2] @ w(3,D) + b ----------
__global__ void k_proj3(const float* __restrict__ in, const float* __restrict__ w,
                        const float* __restrict__ bias, float* __restrict__ out, int M){
  int idx = blockIdx.x*256 + threadIdx.x;
  if (idx >= M*D) return;
  int r = idx / D, d = idx % D;
  const float* ir = in + r*3;
  out[idx] = ir[0]*w[d] + ir[1]*w[D+d] + ir[2]*w[2*D+d] + bias[d];
}

__global__ void k_th(const float* __restrict__ t_in, const float* __restrict__ w1,
                     const float* __restrict__ b1, float* __restrict__ th){
  int idx = blockIdx.x*256 + threadIdx.x;
  if (idx >= NB*D) return;
  int b = idx / D, d = idx % D;
  th[idx] = siluf(t_in[b]*w1[d] + b1[d]);
}

__global__ void k_hs2(const float* __restrict__ h_state, float* __restrict__ hs2){
  int idx = blockIdx.x*256 + threadIdx.x;
  if (idx >= NB*J*2*D) return;
  int r = idx / (2*D), c = idx % (2*D);
  int b = r / J, j = r % J;
  float v;
  if (c < D) v = h_state[(size_t)r*D + c];
  else       v = h_state[((size_t)(b*J) + c_parent[j])*D + (c-D)];
  hs2[idx] = v;
}

__global__ void k_query(const float* __restrict__ h_coarse, const float* __restrict__ h_time,
                        const float* __restrict__ h_dop, const float* __restrict__ h_state,
                        const float* __restrict__ hstruct, const float* __restrict__ jid,
                        const float* __restrict__ mod2, float* __restrict__ x){
  int idx = blockIdx.x*256 + threadIdx.x;
  if (idx >= NB*J*D) return;
  int r = idx / D, d = idx % D;
  int b = r / J, j = r % J;
  float q = h_coarse[idx] + h_time[b*D+d] + h_dop[idx] + h_state[idx] + hstruct[idx] + jid[j*D+d];
  float shift = mod2[(size_t)r*2*D + d];
  float scale = mod2[(size_t)r*2*D + D + d];
  x[idx] = q*(1.f+scale) + shift;
}

// ---------- memory rows for active points only (compacted) ----------
__global__ void k_memact(const float* __restrict__ x_t, const float* __restrict__ pc,
                         const float* __restrict__ pc_w, const float* __restrict__ pc_b,
                         const int* __restrict__ act_idx, const int* __restrict__ act_cnt,
                         const int* __restrict__ act_off, float* __restrict__ mem_act){
  int b = blockIdx.x / CAP, i = blockIdx.x % CAP;
  if (i >= act_cnt[b]) return;
  int n = act_idx[b*CAP+i];
  int t = threadIdx.x; // 128
  __shared__ float sdw[J];
  __shared__ float spi;
  const float* p = pc + ((size_t)b*NP+n)*6;
  if (t < J){
    float x0 = x_t[(b*J+t)*3+0], x1 = x_t[(b*J+t)*3+1], x2 = x_t[(b*J+t)*3+2];
    float p0=p[0], p1=p[1], p2=p[2];
    float d2 = (x0*x0+x1*x1+x2*x2) + (p0*p0+p1*p1+p2*p2) - 2.f*(x0*p0+x1*p1+x2*p2);
    float dist = sqrtf(fmaxf(d2,0.f));
    float sig = c_scale[t]*0.05f;
    sdw[t] = expf(-(dist*dist)/(2.f*sig*sig));
  }
  __syncthreads();
  if (t == 0){ float m = sdw[0]; for (int k = 1; k < J; ++k) m = fmaxf(m, sdw[k]); spi = m; }
  __syncthreads();
  float pi = spi;
  float p0=p[0],p1=p[1],p2=p[2],p3=p[3],p4=p[4],p5=p[5];
  int g = act_off[b] + i;
  float* out = mem_act + (size_t)g*D;
  for (int d = t; d < D; d += 128){
    float acc = pc_b[d] + p0*pc_w[d] + p1*pc_w[D+d] + p2*pc_w[2*D+d]
              + p3*pc_w[3*D+d] + p4*pc_w[4*D+d] + p5*pc_w[5*D+d];
    out[d] = acc * pi;
  }
}

// ---------- generic fp32 tiled GEMM: C = act(A@W + bias [+ res]) ----------
__launch_bounds__(256)
__global__ void k_gemm(const float* __restrict__ A, int lda,
                       const float* __restrict__ W, int ldw,
                       const float* __restrict__ bias,
                       const float* __restrict__ res,
                       float* __restrict__ C, int ldc,
                       int M, int N, int K, int act, const int* __restrict__ Mdev){
  int Meff = Mdev ? *Mdev : M;
  int row0 = blockIdx.y*64, col0 = blockIdx.x*64;
  if (row0 >= Meff) return;
  __shared__ float As[16][68];
  __shared__ float Ws[16][68];
  int tid = threadIdx.x;
  int tx = tid & 15, ty = tid >> 4;
  int arow = tid >> 2;         // 0..63
  int ak   = (tid & 3) * 4;    // 0,4,8,12
  int wr   = tid >> 4;         // 0..15
  int wc   = (tid & 15) * 4;   // 0..60
  float acc[4][4] = {};
  for (int kt = 0; kt < K; kt += 16){
    float4 av = make_float4(0.f,0.f,0.f,0.f);
    int r = row0 + arow;
    if (r < Meff) av = *(const float4*)(A + (size_t)r*lda + kt + ak);
    As[ak+0][arow] = av.x; As[ak+1][arow] = av.y; As[ak+2][arow] = av.z; As[ak+3][arow] = av.w;
    float4 wv = *(const float4*)(W + (size_t)(kt+wr)*ldw + col0 + wc);
    *(float4*)&Ws[wr][wc] = wv;
    __syncthreads();
    #pragma unroll
    for (int k = 0; k < 16; ++k){
      float4 a = *(const float4*)&As[k][ty*4];
      float4 w = *(const float4*)&Ws[k][tx*4];
      float av4[4] = {a.x,a.y,a.z,a.w};
      float wv4[4] = {w.x,w.y,w.z,w.w};
      #pragma unroll
      for (int i = 0; i < 4; ++i)
        #pragma unroll
        for (int jj = 0; jj < 4; ++jj)
          acc[i][jj] += av4[i]*wv4[jj];
    }
    __syncthreads();
  }
  #pragma unroll
  for (int i = 0; i < 4; ++i){
    int r = row0 + ty*4 + i;
    if (r >= Meff) break;
    #pragma unroll
    for (int jj = 0; jj < 4; ++jj){
      int c = col0 + tx*4 + jj;
      float v = acc[i][jj] + bias[c];
      if (res) v += res[(size_t)r*ldc + c];
      if (act == 1) v = v/(1.f+expf(-v));
      else if (act == 2) v = fmaxf(v, 0.f);
      C[(size_t)r*ldc + c] = v;
    }
  }
}

// ---------- LayerNorm over D, per row ----------
__global__ void k_ln(const float* __restrict__ x, const float* __restrict__ s,
                     const float* __restrict__ bb, float* __restrict__ out){
  int r = blockIdx.x; int t = threadIdx.x; // 256
  const float* xr = x + (size_t)r*D;
  float v0 = xr[t], v1 = xr[t+256];
  __shared__ float red[256];
  red[t] = v0+v1; __syncthreads();
  for (int st = 128; st > 0; st >>= 1){ if (t < st) red[t] += red[t+st]; __syncthreads(); }
  float mu = red[0]/(float)D;
  __syncthreads();
  float d0 = v0-mu, d1 = v1-mu;
  red[t] = d0*d0 + d1*d1; __syncthreads();
  for (int st = 128; st > 0; st >>= 1){ if (t < st) red[t] += red[t+st]; __syncthreads(); }
  float var = red[0]/(float)D;
  float rs = rsqrtf(var + 1e-5f);
  out[(size_t)r*D + t]       = d0*rs*s[t]       + bb[t];
  out[(size_t)r*D + t + 256] = d1*rs*s[t+256]   + bb[t+256];
}

// ---------- self-attn: one (b,h) per block, J=27 tokens, topo mask ----------
__launch_bounds__(256)
__global__ void k_selfattn(const float* __restrict__ qkv, float* __restrict__ attno){
  int bh = blockIdx.x; int b = bh / H, h = bh % H;
  int t = threadIdx.x;
  __shared__ float qs[J*DH], ks[J*DH], vs[J*DH];
  __shared__ float ss[J*J];
  for (int e = t; e < J*DH; e += 256){
    int j = e/DH, d = e%DH;
    const float* base = qkv + (size_t)(b*J+j)*1536 + h*DH + d;
    qs[e] = base[0]; ks[e] = base[512]; vs[e] = base[1024];
  }
  __syncthreads();
  for (int e = t; e < J*J; e += 256){
    int qj = e/J, kk = e%J;
    float acc = 0.f;
    for (int d = 0; d < DH; ++d) acc += qs[qj*DH+d]*ks[kk*DH+d];
    float bias = (qj==kk || c_parent[qj]==kk || c_parent[kk]==qj) ? 0.f : NEGF;
    ss[e] = acc*0.125f + bias;
  }
  __syncthreads();
  if (t < J){
    float m = -3.4e38f;
    for (int k = 0; k < J; ++k) m = fmaxf(m, ss[t*J+k]);
    float sum = 0.f;
    for (int k = 0; k < J; ++k){ float e_ = expf(ss[t*J+k]-m); ss[t*J+k] = e_; sum += e_; }
    float inv = 1.f/sum;
    for (int k = 0; k < J; ++k) ss[t*J+k] *= inv;
  }
  __syncthreads();
  for (int e = t; e < J*DH; e += 256){
    int j = e/DH, d = e%DH;
    float acc = 0.f;
    for (int k = 0; k < J; ++k) acc += ss[j*J+k]*vs[k*DH+d];
    attno[(size_t)(b*J+j)*D + h*DH + d] = acc;
  }
}

// ---------- cross-attn over active points only ----------
__launch_bounds__(256)
__global__ void k_crossattn(const float* __restrict__ qbuf, const float* __restrict__ kv_act,
                            const float* __restrict__ x_t, const float* __restrict__ pc,
                            const int* __restrict__ act_idx, const int* __restrict__ act_cnt,
                            const int* __restrict__ act_off, const int* __restrict__ rescue,
                            const int* __restrict__ allm, float* __restrict__ attno){
  int bh = blockIdx.x; int b = bh / H, h = bh % H;
  int t = threadIdx.x;
  int cnt = act_cnt[b], off = act_off[b];
  __shared__ float qs[J*DH];
  __shared__ float ks[CAP*DH];
  __shared__ float pxyz[CAP*3];
  __shared__ float sx[J*3];
  __shared__ int sn[CAP];
  __shared__ float ss[J*CAP];
  if (t < J*3) sx[t] = x_t[b*J*3+t];
  for (int e = t; e < J*DH; e += 256)
    qs[e] = qbuf[(size_t)(b*J + e/DH)*D + h*DH + (e%DH)];
  for (int e = t; e < cnt*DH; e += 256){
    int i = e/DH, d = e%DH;
    ks[e] = kv_act[(size_t)(off+i)*1024 + h*DH + d];
  }
  for (int i = t; i < cnt; i += 256){
    int n = act_idx[b*CAP+i]; sn[i] = n;
    const float* p = pc + ((size_t)b*NP+n)*6;
    pxyz[i*3] = p[0]; pxyz[i*3+1] = p[1]; pxyz[i*3+2] = p[2];
  }
  __syncthreads();
  for (int e = t; e < J*cnt; e += 256){
    int j = e/cnt, i = e%cnt;
    float acc = 0.f;
    for (int d = 0; d < DH; ++d) acc += qs[j*DH+d]*ks[i*DH+d];
    float bias;
    if (allm[b*J+j]) bias = (sn[i] == rescue[b*J+j]) ? 0.f : NEGF;
    else {
      float x0=sx[j*3], x1=sx[j*3+1], x2=sx[j*3+2];
      float p0=pxyz[i*3], p1=pxyz[i*3+1], p2=pxyz[i*3+2];
      float d2 = (x0*x0+x1*x1+x2*x2) + (p0*p0+p1*p1+p2*p2) - 2.f*(x0*p0+x1*p1+x2*p2);
      float dist = sqrtf(fmaxf(d2,0.f));
      float ar = c_scale[j]*0.1f;
      bias = (dist > ar) ? NEGF : 0.f;
    }
    ss[j*CAP+i] = acc*0.125f + bias;
  }
  __syncthreads();
  if (t < J){
    float m = -3.4e38f;
    for (int i = 0; i < cnt; ++i) m = fmaxf(m, ss[t*CAP+i]);
    float sum = 0.f;
    for (int i = 0; i < cnt; ++i){ float e_ = expf(ss[t*CAP+i]-m); ss[t*CAP+i] = e_; sum += e_; }
    float inv = 1.f/sum;
    for (int i = 0; i < cnt; ++i) ss[t*CAP+i] *= inv;
  }
  __syncthreads();
  for (int e = t; e < J*DH; e += 256){
    int j = e/DH, d = e%DH;
    float acc = 0.f;
    for (int i = 0; i < cnt; ++i)
      acc += ss[j*CAP+i]*kv_act[(size_t)(off+i)*1024 + 512 + h*DH + d];
    attno[(size_t)(b*J+j)*D + h*DH + d] = acc;
  }
}

// ---------- final vel projection (D -> 3) ----------
__global__ void k_vel(const float* __restrict__ x, const float* __restrict__ vel_w,
                      const float* __restrict__ vel_b, float* __restrict__ out){
  int r = blockIdx.x; int t = threadIdx.x; // 192 = 3 waves
  int c = t >> 6; int lane = t & 63;
  float acc = 0.f;
  const float* xr = x + (size_t)r*D;
  for (int d = lane; d < D; d += 64) acc += xr[d]*vel_w[d*3+c];
  for (int s = 32; s > 0; s >>= 1) acc += __shfl_down(acc, s);
  if (lane == 0) out[r*3+c] = acc + vel_b[c];
}

// ============================================================================
static void gemm(const float* A, int lda, const float* W, int ldw, const float* bias,
                 const float* res, float* C, int ldc, int M, int N, int K, int act,
                 const int* Mdev, hipStream_t s){
  dim3 g(N/64, (M+63)/64);
  k_gemm<<<g, 256, 0, s>>>(A, lda, W, ldw, bias, res, C, ldc, M, N, K, act, Mdev);
}

extern "C" void kernel_launch(void* const* d_in, const int* in_sizes, int n_in,
                              void* d_out, int out_size, void* d_ws, size_t ws_size,
                              hipStream_t stream){
  const float* x_t        = (const float*)d_in[0];
  const float* t_in       = (const float*)d_in[1];
  const float* coarse     = (const float*)d_in[2];
  const float* radar      = (const float*)d_in[3];
  const float* pc_w       = (const float*)d_in[4];
  const float* pc_b       = (const float*)d_in[5];
  const float* coarse_w   = (const float*)d_in[6];
  const float* coarse_b   = (const float*)d_in[7];
  const float* state_w    = (const float*)d_in[8];
  const float* state_b    = (const float*)d_in[9];
  const float* jid_emb    = (const float*)d_in[10];
  const float* dop_w1     = (const float*)d_in[11];
  const float* dop_b1     = (const float*)d_in[12];
  const float* dop_w2     = (const float*)d_in[13];
  const float* dop_b2     = (const float*)d_in[14];
  const float* time_w1    = (const float*)d_in[15];
  const float* time_b1    = (const float*)d_in[16];
  const float* time_w2    = (const float*)d_in[17];
  const float* time_b2    = (const float*)d_in[18];
  const float* mod_w1     = (const float*)d_in[19];
  const float* mod_b1     = (const float*)d_in[20];
  const float* mod_w2     = (const float*)d_in[21];
  const float* mod_b2     = (const float*)d_in[22];
  const float* diff_w     = (const float*)d_in[23];
  const float* diff_b     = (const float*)d_in[24];
  const float* vel_w      = (const float*)d_in[25];
  const float* vel_b      = (const float*)d_in[26];
  const float* sa_qkv_w   = (const float*)d_in[27];
  const float* sa_qkv_b   = (const float*)d_in[28];
  const float* sa_out_w   = (const float*)d_in[29];
  const float* sa_out_b   = (const float*)d_in[30];
  const float* ca_qkv_w   = (const float*)d_in[31];
  const float* ca_qkv_b   = (const float*)d_in[32];
  const float* ca_out_w   = (const float*)d_in[33];
  const float* ca_out_b   = (const float*)d_in[34];
  const float* ff1_w      = (const float*)d_in[35];
  const float* ff1_b      = (const float*)d_in[36];
  const float* ff2_w      = (const float*)d_in[37];
  const float* ff2_b      = (const float*)d_in[38];
  const float* ln1_s      = (const float*)d_in[39];
  const float* ln1_b      = (const float*)d_in[40];
  const float* ln2_s      = (const float*)d_in[41];
  const float* ln2_b      = (const float*)d_in[42];
  const float* ln3_s      = (const float*)d_in[43];
  const float* ln3_b      = (const float*)d_in[44];
  (void)in_sizes; (void)n_in; (void)out_size; (void)ws_size;

  const int R = NB*J; // 1728 rows

  // bump allocator over d_ws (256B aligned)
  char* wp = (char*)d_ws;
  auto alloc = [&](size_t bytes)->void*{
    void* r = (void*)wp;
    wp += (bytes + 255) & ~(size_t)255;
    return r;
  };
  float*        denom_sum = (float*)alloc(R*4);
  int*          rescue    = (int*)  alloc(R*4);
  int*          allm      = (int*)  alloc(R*4);
  unsigned int* bitmap    = (unsigned int*)alloc(NB*(NP/32)*4);
  int*          act_idx   = (int*)  alloc(NB*CAP*4);
  int*          act_cnt   = (int*)  alloc(NB*4);
  int*          act_off   = (int*)  alloc(NB*4);
  int*          act_total = (int*)  alloc(64);
  float* Gp       = (float*)alloc((size_t)NB*NCH*J*64*4);
  float* h_dop    = (float*)alloc((size_t)R*D*4);
  float* h_state  = (float*)alloc((size_t)R*D*4);
  float* h_coarse = (float*)alloc((size_t)R*D*4);
  float* hstruct  = (float*)alloc((size_t)R*D*4);
  float* xres     = (float*)alloc((size_t)R*D*4);
  float* hbuf     = (float*)alloc((size_t)R*D*4);
  float* attno    = (float*)alloc((size_t)R*D*4);
  float* qbuf     = (float*)alloc((size_t)R*D*4);
  float* th       = (float*)alloc((size_t)NB*D*4);
  float* h_time   = (float*)alloc((size_t)NB*D*4);
  float* mod1     = (float*)alloc((size_t)R*2*D*4);   // ffh aliases mod1+mod2
  float* mod2     = (float*)alloc((size_t)R*2*D*4);
  float* qkv      = (float*)alloc((size_t)R*3*D*4);   // hs2 aliases qkv
  float* mem_act  = (float*)alloc((size_t)NB*CAP*D*4);
  float* kv_act   = (float*)alloc((size_t)NB*CAP*2*D*4);
  float* ffh = mod1;       // (R,2048) = mod1(R,1024)+mod2(R,1024) contiguous
  float* hs2 = qkv;        // (R,1024) fits in qkv (R,1536)

  // ---- stage 0: masks / active set / h_dop ----
  hipMemsetAsync(bitmap, 0, NB*(NP/32)*4, stream);
  k_perj<<<R, 256, 0, stream>>>(x_t, radar, denom_sum, rescue, allm, bitmap);
  k_compact<<<NB, 64, 0, stream>>>(bitmap, act_idx, act_cnt);
  k_scan<<<1, 64, 0, stream>>>(act_cnt, act_off, act_total);
  k_gpart<<<dim3(NB, NCH), 256, 0, stream>>>(x_t, radar, dop_w1, dop_b1, Gp);
  k_hdop2<<<R, 64, 0, stream>>>(Gp, dop_w2, dop_b2, denom_sum, h_dop);

  // ---- stage 1: query build ----
  k_proj3<<<(R*D+255)/256, 256, 0, stream>>>(x_t, state_w, state_b, h_state, R);
  k_proj3<<<(R*D+255)/256, 256, 0, stream>>>(coarse, coarse_w, coarse_b, h_coarse, R);
  k_th<<<(NB*D+255)/256, 256, 0, stream>>>(t_in, time_w1, time_b1, th);
  gemm(th, D, time_w2, D, time_b2, nullptr, h_time, D, NB, D, D, 0, nullptr, stream);
  gemm(h_state, D, mod_w1, 2*D, mod_b1, nullptr, mod1, 2*D, R, 2*D, D, 1, nullptr, stream);
  gemm(mod1, 2*D, mod_w2, 2*D, mod_b2, nullptr, mod2, 2*D, R, 2*D, 2*D, 0, nullptr, stream);
  k_hs2<<<(R*2*D+255)/256, 256, 0, stream>>>(h_state, hs2);
  gemm(hs2, 2*D, diff_w, D, diff_b, nullptr, hstruct, D, R, D, 2*D, 0, nullptr, stream);
  k_query<<<(R*D+255)/256, 256, 0, stream>>>(h_coarse, h_time, h_dop, h_state, hstruct,
                                             jid_emb, mod2, xres);
  k_memact<<<NB*CAP, 128, 0, stream>>>(x_t, radar, pc_w, pc_b, act_idx, act_cnt, act_off, mem_act);

  // ---- stage 2: transformer layers ----
  for (int l = 0; l < NLAYER; ++l){
    k_ln<<<R, 256, 0, stream>>>(xres, ln1_s + l*D, ln1_b + l*D, hbuf);
    gemm(hbuf, D, sa_qkv_w + (size_t)l*D*3*D, 3*D, sa_qkv_b + l*3*D, nullptr,
         qkv, 3*D, R, 3*D, D, 0, nullptr, stream);
    k_selfattn<<<NB*H, 256, 0, stream>>>(qkv, attno);
    gemm(attno, D, sa_out_w + (size_t)l*D*D, D, sa_out_b + l*D, xres,
         xres, D, R, D, D, 0, nullptr, stream);

    k_ln<<<R, 256, 0, stream>>>(xres, ln2_s + l*D, ln2_b + l*D, hbuf);
    gemm(hbuf, D, ca_qkv_w + (size_t)l*D*3*D, 3*D, ca_qkv_b + l*3*D, nullptr,
         qbuf, D, R, D, D, 0, nullptr, stream);
    gemm(mem_act, D, ca_qkv_w + (size_t)l*D*3*D + D, 3*D, ca_qkv_b + l*3*D + D, nullptr,
         kv_act, 2*D, NB*CAP, 2*D, D, 0, act_total, stream);
    k_crossattn<<<NB*H, 256, 0, stream>>>(qbuf, kv_act, x_t, radar, act_idx, act_cnt,
                                          act_off, rescue, allm, attno);
    gemm(attno, D, ca_out_w + (size_t)l*D*D, D, ca_out_b + l*D, xres,
         xres, D, R, D, D, 0, nullptr, stream);

    k_ln<<<R, 256, 0, stream>>>(xres, ln3_s + l*D, ln3_b + l*D, hbuf);
    gemm(hbuf, D, ff1_w + (size_t)l*D*DFF, DFF, ff1_b + l*DFF, nullptr,
         ffh, DFF, R, DFF, D, 2, nullptr, stream);
    gemm(ffh, DFF, ff2_w + (size_t)l*DFF*D, D, ff2_b + l*D, xres,
         xres, D, R, D, DFF, 0, nullptr, stream);
  }

  k_vel<<<R, 192, 0, stream>>>(xres, vel_w, vel_b, (float*)d_out);
}

// Round 2
// 2061.044 us; speedup vs baseline: 1.4717x; 1.4717x over previous
//
#include <hip/hip_runtime.h>

#define J 27
#define D 512
#define H 8
#define DH 64
#define NLAYER 6
#define DFF 2048
#define NB 64
#define NP 2048
#define CAP 128
#define GCH 16
#define GPTS 128
#define NEGF -1000000000.0f

__constant__ int c_parent[J] = {0,0,1,2,3,4,5,6,7,8,8,3,11,12,13,14,15,15,0,18,19,20,0,22,23,24,3};
__constant__ float c_scale[J] = {0.6f,0.6f,0.6f,0.6f,1.f,1.f,1.f,1.f,1.f,1.5f,1.5f,1.f,1.f,1.f,1.f,1.f,
                                 1.5f,1.5f,0.6f,1.f,1.5f,1.5f,0.6f,1.f,1.5f,1.5f,1.5f};

__device__ __forceinline__ float siluf(float x){ return x/(1.f+expf(-x)); }

typedef __attribute__((ext_vector_type(8))) __bf16 bf16x8;
typedef __attribute__((ext_vector_type(4))) float f32x4;

__device__ __forceinline__ unsigned short f2bf(float f){
  union { float f; unsigned u; } x; x.f = f;
  unsigned r = x.u + 0x7FFFu + ((x.u >> 16) & 1u);
  return (unsigned short)(r >> 16);
}
__device__ __forceinline__ float bf2f(unsigned short h){
  union { unsigned u; float f; } x; x.u = ((unsigned)h) << 16; return x.f;
}

// ---------- per (b,j): denom sum, rescue idx (argmin dist), allmask, active-bitmap marks ----------
__global__ void k_perj(const float* __restrict__ x_t, const float* __restrict__ pc,
                       float* __restrict__ denom_sum, int* __restrict__ rescue,
                       int* __restrict__ allm, unsigned int* __restrict__ bitmap){
  int bj = blockIdx.x; int b = bj / J, j = bj % J;
  int t = threadIdx.x;
  float x0 = x_t[(b*J+j)*3+0];
  float x1 = x_t[(b*J+j)*3+1];
  float x2 = x_t[(b*J+j)*3+2];
  float sx = x0*x0+x1*x1+x2*x2;
  float ar = c_scale[j]*0.1f;
  float sig = ar*0.5f;
  float twos2 = 2.f*sig*sig;
  float sum = 0.f, bmin = 3.4e38f; int bidx = NP; int any = 0;
  for (int n = t; n < NP; n += 256){
    const float* p = pc + ((size_t)b*NP + n)*6;
    float p0=p[0], p1=p[1], p2=p[2];
    float d2 = sx + (p0*p0+p1*p1+p2*p2) - 2.f*(x0*p0+x1*p1+x2*p2);
    float dist = sqrtf(fmaxf(d2, 0.f));
    sum += expf(-(dist*dist)/twos2);
    if (dist < bmin){ bmin = dist; bidx = n; }
    if (dist <= ar){ any = 1; atomicOr(&bitmap[b*(NP/32)+(n>>5)], 1u<<(n&31)); }
  }
  __shared__ float ssum[256]; __shared__ float smin[256];
  __shared__ int sidx[256]; __shared__ int sany[256];
  ssum[t]=sum; smin[t]=bmin; sidx[t]=bidx; sany[t]=any;
  __syncthreads();
  for (int s = 128; s > 0; s >>= 1){
    if (t < s){
      ssum[t] += ssum[t+s];
      if (smin[t+s] < smin[t] || (smin[t+s]==smin[t] && sidx[t+s] < sidx[t])){ smin[t]=smin[t+s]; sidx[t]=sidx[t+s]; }
      sany[t] |= sany[t+s];
    }
    __syncthreads();
  }
  if (t == 0){
    denom_sum[bj] = ssum[0];
    rescue[bj] = sidx[0];
    allm[bj] = sany[0] ? 0 : 1;
    if (!sany[0]) atomicOr(&bitmap[b*(NP/32)+(sidx[0]>>5)], 1u<<(sidx[0]&31));
  }
}

// ---------- ordered compaction of active bitmap -> per-batch index list (1 wave / batch) ----------
__global__ void k_compact(const unsigned int* __restrict__ bitmap, int* __restrict__ act_idx,
                          int* __restrict__ act_cnt){
  int b = blockIdx.x; int t = threadIdx.x; // 64 threads = 1 wave
  unsigned int w = bitmap[b*(NP/32)+t];
  int c = __popc(w);
  int off = c;
  for (int s = 1; s < 64; s <<= 1){
    int v = __shfl_up(off, s);
    if (t >= s) off += v;
  }
  int total = __shfl(off, 63);
  off -= c; // exclusive
  int base = off;
  for (int bit = 0; bit < 32; ++bit){
    if (w & (1u<<bit)){
      if (base < CAP) act_idx[b*CAP+base] = t*32+bit;
      base++;
    }
  }
  if (t == 0) act_cnt[b] = total > CAP ? CAP : total;
}

__global__ void k_scan(const int* __restrict__ act_cnt, int* __restrict__ act_off,
                       int* __restrict__ act_total){
  if (threadIdx.x == 0){
    int s = 0;
    for (int b = 0; b < NB; ++b){ act_off[b] = s; s += act_cnt[b]; }
    act_total[0] = s;
  }
}

// ---------- G[b,ch,j,h] = sum_n dw[b,j,n] * silu(dop*w1[h]+b1[h])  (fully parallel chunks) ----------
__launch_bounds__(256)
__global__ void k_gpart(const float* __restrict__ x_t, const float* __restrict__ pc,
                        const float* __restrict__ dop_w1, const float* __restrict__ dop_b1,
                        float* __restrict__ Gp){
  int b = blockIdx.x, ch = blockIdx.y; int t = threadIdx.x;
  __shared__ float sx[J*3];
  __shared__ float w1s[64], b1s[64];
  __shared__ float spx[GPTS], spy[GPTS], spz[GPTS], sdp[GPTS];
  __shared__ float hid[GPTS*65];
  __shared__ float dws[J*129];
  if (t < J*3) sx[t] = x_t[b*J*3 + t];
  if (t < 64){ w1s[t] = dop_w1[t]; b1s[t] = dop_b1[t]; }
  int n0 = ch*GPTS;
  if (t < GPTS){
    const float* p = pc + ((size_t)b*NP + n0 + t)*6;
    float2 f0 = *(const float2*)p;
    float2 f1 = *(const float2*)(p+2);
    spx[t]=f0.x; spy[t]=f0.y; spz[t]=f1.x; sdp[t]=f1.y;
  }
  __syncthreads();
  { // hid: 2 threads per point, 32 h each
    int p = t>>1, h0 = (t&1)*32;
    float dop = sdp[p];
    #pragma unroll 8
    for (int i = 0; i < 32; ++i){
      int h = h0 + i;
      hid[p*65+h] = siluf(dop*w1s[h]+b1s[h]);
    }
  }
  for (int e = t; e < J*GPTS; e += 256){
    int j = e>>7, p = e&127;
    float x0=sx[j*3], x1=sx[j*3+1], x2=sx[j*3+2];
    float p0=spx[p], p1=spy[p], p2=spz[p];
    float d2 = (x0*x0+x1*x1+x2*x2) + (p0*p0+p1*p1+p2*p2) - 2.f*(x0*p0+x1*p1+x2*p2);
    float dist = sqrtf(fmaxf(d2, 0.f));
    float sig = c_scale[j]*0.05f;
    dws[j*129+p] = expf(-(dist*dist)/(2.f*sig*sig));
  }
  __syncthreads();
  // G[j][h] = sum_p dws[j][p]*hid[p][h]; thread: h = t&63, j in {jb, jb+4, ...}
  int h = t & 63, jb = t >> 6;
  float acc[7] = {0.f,0.f,0.f,0.f,0.f,0.f,0.f};
  for (int p = 0; p < GPTS; ++p){
    float hv = hid[p*65+h];
    #pragma unroll
    for (int i = 0; i < 7; ++i){
      int j = jb + 4*i;
      if (j < J) acc[i] += dws[j*129+p]*hv;
    }
  }
  float* out = Gp + ((size_t)(b*GCH+ch))*J*64;
  #pragma unroll
  for (int i = 0; i < 7; ++i){
    int j = jb + 4*i;
    if (j < J) out[j*64+h] = acc[i];
  }
}

// ---------- h_dop[b,j,:] = (G @ w2 + S*b2) / (S + 1e-6) ----------
__global__ void k_hdop2(const float* __restrict__ Gp, const float* __restrict__ dop_w2,
                        const float* __restrict__ dop_b2, const float* __restrict__ denom_sum,
                        float* __restrict__ h_dop){
  int bj = blockIdx.x; int b = bj/J, j = bj%J; int t = threadIdx.x; // 64
  __shared__ float G[64];
  float g = 0.f;
  for (int c = 0; c < GCH; ++c) g += Gp[((size_t)(b*GCH+c)*J + j)*64 + t];
  G[t] = g; __syncthreads();
  float S = denom_sum[bj];
  float inv = 1.f/(S + 1e-6f);
  float* out = h_dop + (size_t)bj*D;
  for (int u = 0; u < D/64; ++u){
    int d = u*64 + t;
    float acc = 0.f;
    for (int hh = 0; hh < 64; ++hh) acc += G[hh]*dop_w2[hh*D+d];
    out[d] = (acc + S*dop_b2[d]) * inv;
  }
}

// ---------- out[r,d] = in[r,0..2] @ w(3,D) + b ----------
__global__ void k_proj3(const float* __restrict__ in, const float* __restrict__ w,
                        const float* __restrict__ bias, float* __restrict__ out, int M){
  int idx = blockIdx.x*256 + threadIdx.x;
  if (idx >= M*D) return;
  int r = idx / D, d = idx % D;
  const float* ir = in + r*3;
  out[idx] = ir[0]*w[d] + ir[1]*w[D+d] + ir[2]*w[2*D+d] + bias[d];
}

__global__ void k_th(const float* __restrict__ t_in, const float* __restrict__ w1,
                     const float* __restrict__ b1, float* __restrict__ th){
  int idx = blockIdx.x*256 + threadIdx.x;
  if (idx >= NB*D) return;
  int b = idx / D, d = idx % D;
  th[idx] = siluf(t_in[b]*w1[d] + b1[d]);
}

__global__ void k_hs2(const float* __restrict__ h_state, float* __restrict__ hs2){
  int idx = blockIdx.x*256 + threadIdx.x;
  if (idx >= NB*J*2*D) return;
  int r = idx / (2*D), c = idx % (2*D);
  int b = r / J, j = r % J;
  float v;
  if (c < D) v = h_state[(size_t)r*D + c];
  else       v = h_state[((size_t)(b*J) + c_parent[j])*D + (c-D)];
  hs2[idx] = v;
}

__global__ void k_query(const float* __restrict__ h_coarse, const float* __restrict__ h_time,
                        const float* __restrict__ h_dop, const float* __restrict__ h_state,
                        const float* __restrict__ hstruct, const float* __restrict__ jid,
                        const float* __restrict__ mod2, float* __restrict__ x){
  int idx = blockIdx.x*256 + threadIdx.x;
  if (idx >= NB*J*D) return;
  int r = idx / D, d = idx % D;
  int b = r / J, j = r % J;
  float q = h_coarse[idx] + h_time[b*D+d] + h_dop[idx] + h_state[idx] + hstruct[idx] + jid[j*D+d];
  float shift = mod2[(size_t)r*2*D + d];
  float scale = mod2[(size_t)r*2*D + D + d];
  x[idx] = q*(1.f+scale) + shift;
}

// ---------- memory rows for active points only (compacted) ----------
__global__ void k_memact(const float* __restrict__ x_t, const float* __restrict__ pc,
                         const float* __restrict__ pc_w, const float* __restrict__ pc_b,
                         const int* __restrict__ act_idx, const int* __restrict__ act_cnt,
                         const int* __restrict__ act_off, float* __restrict__ mem_act){
  int b = blockIdx.x / CAP, i = blockIdx.x % CAP;
  if (i >= act_cnt[b]) return;
  int n = act_idx[b*CAP+i];
  int t = threadIdx.x; // 128
  __shared__ float sdw[J];
  __shared__ float spi;
  const float* p = pc + ((size_t)b*NP+n)*6;
  if (t < J){
    float x0 = x_t[(b*J+t)*3+0], x1 = x_t[(b*J+t)*3+1], x2 = x_t[(b*J+t)*3+2];
    float p0=p[0], p1=p[1], p2=p[2];
    float d2 = (x0*x0+x1*x1+x2*x2) + (p0*p0+p1*p1+p2*p2) - 2.f*(x0*p0+x1*p1+x2*p2);
    float dist = sqrtf(fmaxf(d2,0.f));
    float sig = c_scale[t]*0.05f;
    sdw[t] = expf(-(dist*dist)/(2.f*sig*sig));
  }
  __syncthreads();
  if (t == 0){ float m = sdw[0]; for (int k = 1; k < J; ++k) m = fmaxf(m, sdw[k]); spi = m; }
  __syncthreads();
  float pi = spi;
  float p0=p[0],p1=p[1],p2=p[2],p3=p[3],p4=p[4],p5=p[5];
  int g = act_off[b] + i;
  float* out = mem_act + (size_t)g*D;
  for (int d = t; d < D; d += 128){
    float acc = pc_b[d] + p0*pc_w[d] + p1*pc_w[D+d] + p2*pc_w[2*D+d]
              + p3*pc_w[3*D+d] + p4*pc_w[4*D+d] + p5*pc_w[5*D+d];
    out[d] = acc * pi;
  }
}

// ---------- MFMA bf16 hi/lo split GEMM (fp32-accurate): C = act(A@W + bias [+ res]) ----------
// A: fp32 [M][lda], W: fp32 [K][ldw] row-major. 64x64 tile, BK=32, 4 waves (2x2),
// each wave 32x32 via 2x2 frags of v_mfma_f32_16x16x32_bf16.
// 3-term: A@B ~= Ahi*Bhi + Ahi*Blo + Alo*Bhi  (rel err ~2^-17)
#define GSTRIDE 40  // bf16 elems per LDS row (32 + 8 pad) -> 80B, 16B-aligned frags
__launch_bounds__(256)
__global__ void k_gemm(const float* __restrict__ A, int lda,
                       const float* __restrict__ W, int ldw,
                       const float* __restrict__ bias,
                       const float* __restrict__ res,
                       float* __restrict__ C, int ldc,
                       int M, int N, int K, int act, const int* __restrict__ Mdev){
  int Meff = Mdev ? *Mdev : M;
  int row0 = blockIdx.y*64, col0 = blockIdx.x*64;
  if (row0 >= Meff) return;
  __shared__ unsigned short Ah[64*GSTRIDE], Al[64*GSTRIDE];
  __shared__ unsigned short Bh[64*GSTRIDE], Bl[64*GSTRIDE];
  int t = threadIdx.x;
  int lane = t & 63, w = t >> 6;
  int wr = w >> 1, wc = w & 1;
  int ar  = t >> 2,  akq = (t & 3) * 8;   // A staging: row, k-quad
  int bcol = t & 63, bkq = (t >> 6) * 8;  // B staging: col, k-quad
  int fr = lane & 15;                      // row/col within 16x16 frag
  int fk = (lane >> 4) * 8;                // frag k offset
  f32x4 acc[2][2] = {};
  for (int kt = 0; kt < K; kt += 32){
    // ---- stage A (hi/lo) ----
    {
      float va[8] = {0.f,0.f,0.f,0.f,0.f,0.f,0.f,0.f};
      int r = row0 + ar;
      if (r < Meff){
        const float* ap = A + (size_t)r*lda + kt + akq;
        float4 v0 = *(const float4*)ap;
        float4 v1 = *(const float4*)(ap+4);
        va[0]=v0.x; va[1]=v0.y; va[2]=v0.z; va[3]=v0.w;
        va[4]=v1.x; va[5]=v1.y; va[6]=v1.z; va[7]=v1.w;
      }
      unsigned hp[4], lp[4];
      #pragma unroll
      for (int i = 0; i < 4; ++i){
        unsigned short ha = f2bf(va[2*i]),   hb = f2bf(va[2*i+1]);
        unsigned short la = f2bf(va[2*i]  - bf2f(ha));
        unsigned short lb = f2bf(va[2*i+1]- bf2f(hb));
        hp[i] = (unsigned)ha | ((unsigned)hb << 16);
        lp[i] = (unsigned)la | ((unsigned)lb << 16);
      }
      int o = ar*GSTRIDE + akq;
      *(uint4*)&Ah[o] = make_uint4(hp[0],hp[1],hp[2],hp[3]);
      *(uint4*)&Al[o] = make_uint4(lp[0],lp[1],lp[2],lp[3]);
    }
    // ---- stage B (transpose to col-major-k-contiguous, hi/lo) ----
    {
      const float* wp = W + (size_t)(kt + bkq)*ldw + col0 + bcol;
      float vb[8];
      #pragma unroll
      for (int i = 0; i < 8; ++i) vb[i] = wp[(size_t)i*ldw];
      unsigned hp[4], lp[4];
      #pragma unroll
      for (int i = 0; i < 4; ++i){
        unsigned short ha = f2bf(vb[2*i]),   hb = f2bf(vb[2*i+1]);
        unsigned short la = f2bf(vb[2*i]  - bf2f(ha));
        unsigned short lb = f2bf(vb[2*i+1]- bf2f(hb));
        hp[i] = (unsigned)ha | ((unsigned)hb << 16);
        lp[i] = (unsigned)la | ((unsigned)lb << 16);
      }
      int o = bcol*GSTRIDE + bkq;
      *(uint4*)&Bh[o] = make_uint4(hp[0],hp[1],hp[2],hp[3]);
      *(uint4*)&Bl[o] = make_uint4(lp[0],lp[1],lp[2],lp[3]);
    }
    __syncthreads();
    // ---- fragments + MFMA ----
    bf16x8 a_h[2], a_l[2], b_h[2], b_l[2];
    #pragma unroll
    for (int m = 0; m < 2; ++m){
      int o = (wr*32 + m*16 + fr)*GSTRIDE + fk;
      a_h[m] = *(const bf16x8*)&Ah[o];
      a_l[m] = *(const bf16x8*)&Al[o];
    }
    #pragma unroll
    for (int n = 0; n < 2; ++n){
      int o = (wc*32 + n*16 + fr)*GSTRIDE + fk;
      b_h[n] = *(const bf16x8*)&Bh[o];
      b_l[n] = *(const bf16x8*)&Bl[o];
    }
    #pragma unroll
    for (int m = 0; m < 2; ++m)
      #pragma unroll
      for (int n = 0; n < 2; ++n){
        acc[m][n] = __builtin_amdgcn_mfma_f32_16x16x32_bf16(a_l[m], b_h[n], acc[m][n], 0, 0, 0);
        acc[m][n] = __builtin_amdgcn_mfma_f32_16x16x32_bf16(a_h[m], b_l[n], acc[m][n], 0, 0, 0);
        acc[m][n] = __builtin_amdgcn_mfma_f32_16x16x32_bf16(a_h[m], b_h[n], acc[m][n], 0, 0, 0);
      }
    __syncthreads();
  }
  // ---- epilogue: C/D layout col=lane&15, row=(lane>>4)*4+q ----
  int er = (lane >> 4) * 4, ec = lane & 15;
  #pragma unroll
  for (int m = 0; m < 2; ++m){
    #pragma unroll
    for (int q = 0; q < 4; ++q){
      int r = row0 + wr*32 + m*16 + er + q;
      if (r >= Meff) continue;
      #pragma unroll
      for (int n = 0; n < 2; ++n){
        int c = col0 + wc*32 + n*16 + ec;
        float v = acc[m][n][q] + bias[c];
        if (res) v += res[(size_t)r*ldc + c];
        if (act == 1) v = v/(1.f+expf(-v));
        else if (act == 2) v = fmaxf(v, 0.f);
        C[(size_t)r*ldc + c] = v;
      }
    }
  }
}

// ---------- LayerNorm over D, per row ----------
__global__ void k_ln(const float* __restrict__ x, const float* __restrict__ s,
                     const float* __restrict__ bb, float* __restrict__ out){
  int r = blockIdx.x; int t = threadIdx.x; // 256
  const float* xr = x + (size_t)r*D;
  float v0 = xr[t], v1 = xr[t+256];
  __shared__ float red[256];
  red[t] = v0+v1; __syncthreads();
  for (int st = 128; st > 0; st >>= 1){ if (t < st) red[t] += red[t+st]; __syncthreads(); }
  float mu = red[0]/(float)D;
  __syncthreads();
  float d0 = v0-mu, d1 = v1-mu;
  red[t] = d0*d0 + d1*d1; __syncthreads();
  for (int st = 128; st > 0; st >>= 1){ if (t < st) red[t] += red[t+st]; __syncthreads(); }
  float var = red[0]/(float)D;
  float rs = rsqrtf(var + 1e-5f);
  out[(size_t)r*D + t]       = d0*rs*s[t]       + bb[t];
  out[(size_t)r*D + t + 256] = d1*rs*s[t+256]   + bb[t+256];
}

// ---------- self-attn: one (b,h) per block, J=27 tokens, topo mask ----------
__launch_bounds__(256)
__global__ void k_selfattn(const float* __restrict__ qkv, float* __restrict__ attno){
  int bh = blockIdx.x; int b = bh / H, h = bh % H;
  int t = threadIdx.x;
  __shared__ float qs[J*DH], ks[J*DH], vs[J*DH];
  __shared__ float ss[J*J];
  for (int e = t; e < J*DH; e += 256){
    int j = e/DH, d = e%DH;
    const float* base = qkv + (size_t)(b*J+j)*1536 + h*DH + d;
    qs[e] = base[0]; ks[e] = base[512]; vs[e] = base[1024];
  }
  __syncthreads();
  for (int e = t; e < J*J; e += 256){
    int qj = e/J, kk = e%J;
    float acc = 0.f;
    for (int d = 0; d < DH; ++d) acc += qs[qj*DH+d]*ks[kk*DH+d];
    float bias = (qj==kk || c_parent[qj]==kk || c_parent[kk]==qj) ? 0.f : NEGF;
    ss[e] = acc*0.125f + bias;
  }
  __syncthreads();
  if (t < J){
    float m = -3.4e38f;
    for (int k = 0; k < J; ++k) m = fmaxf(m, ss[t*J+k]);
    float sum = 0.f;
    for (int k = 0; k < J; ++k){ float e_ = expf(ss[t*J+k]-m); ss[t*J+k] = e_; sum += e_; }
    float inv = 1.f/sum;
    for (int k = 0; k < J; ++k) ss[t*J+k] *= inv;
  }
  __syncthreads();
  for (int e = t; e < J*DH; e += 256){
    int j = e/DH, d = e%DH;
    float acc = 0.f;
    for (int k = 0; k < J; ++k) acc += ss[j*J+k]*vs[k*DH+d];
    attno[(size_t)(b*J+j)*D + h*DH + d] = acc;
  }
}

// ---------- cross-attn over active points only ----------
__launch_bounds__(256)
__global__ void k_crossattn(const float* __restrict__ qbuf, const float* __restrict__ kv_act,
                            const float* __restrict__ x_t, const float* __restrict__ pc,
                            const int* __restrict__ act_idx, const int* __restrict__ act_cnt,
                            const int* __restrict__ act_off, const int* __restrict__ rescue,
                            const int* __restrict__ allm, float* __restrict__ attno){
  int bh = blockIdx.x; int b = bh / H, h = bh % H;
  int t = threadIdx.x;
  int cnt = act_cnt[b], off = act_off[b];
  __shared__ float qs[J*DH];
  __shared__ float ks[CAP*DH];
  __shared__ float pxyz[CAP*3];
  __shared__ float sx[J*3];
  __shared__ int sn[CAP];
  __shared__ float ss[J*CAP];
  if (t < J*3) sx[t] = x_t[b*J*3+t];
  for (int e = t; e < J*DH; e += 256)
    qs[e] = qbuf[(size_t)(b*J + e/DH)*D + h*DH + (e%DH)];
  for (int e = t; e < cnt*DH; e += 256){
    int i = e/DH, d = e%DH;
    ks[e] = kv_act[(size_t)(off+i)*1024 + h*DH + d];
  }
  for (int i = t; i < cnt; i += 256){
    int n = act_idx[b*CAP+i]; sn[i] = n;
    const float* p = pc + ((size_t)b*NP+n)*6;
    pxyz[i*3] = p[0]; pxyz[i*3+1] = p[1]; pxyz[i*3+2] = p[2];
  }
  __syncthreads();
  for (int e = t; e < J*cnt; e += 256){
    int j = e/cnt, i = e%cnt;
    float acc = 0.f;
    for (int d = 0; d < DH; ++d) acc += qs[j*DH+d]*ks[i*DH+d];
    float bias;
    if (allm[b*J+j]) bias = (sn[i] == rescue[b*J+j]) ? 0.f : NEGF;
    else {
      float x0=sx[j*3], x1=sx[j*3+1], x2=sx[j*3+2];
      float p0=pxyz[i*3], p1=pxyz[i*3+1], p2=pxyz[i*3+2];
      float d2 = (x0*x0+x1*x1+x2*x2) + (p0*p0+p1*p1+p2*p2) - 2.f*(x0*p0+x1*p1+x2*p2);
      float dist = sqrtf(fmaxf(d2,0.f));
      float ar = c_scale[j]*0.1f;
      bias = (dist > ar) ? NEGF : 0.f;
    }
    ss[j*CAP+i] = acc*0.125f + bias;
  }
  __syncthreads();
  if (t < J){
    float m = -3.4e38f;
    for (int i = 0; i < cnt; ++i) m = fmaxf(m, ss[t*CAP+i]);
    float sum = 0.f;
    for (int i = 0; i < cnt; ++i){ float e_ = expf(ss[t*CAP+i]-m); ss[t*CAP+i] = e_; sum += e_; }
    float inv = 1.f/sum;
    for (int i = 0; i < cnt; ++i) ss[t*CAP+i] *= inv;
  }
  __syncthreads();
  for (int e = t; e < J*DH; e += 256){
    int j = e/DH, d = e%DH;
    float acc = 0.f;
    for (int i = 0; i < cnt; ++i)
      acc += ss[j*CAP+i]*kv_act[(size_t)(off+i)*1024 + 512 + h*DH + d];
    attno[(size_t)(b*J+j)*D + h*DH + d] = acc;
  }
}

// ---------- final vel projection (D -> 3) ----------
__global__ void k_vel(const float* __restrict__ x, const float* __restrict__ vel_w,
                      const float* __restrict__ vel_b, float* __restrict__ out){
  int r = blockIdx.x; int t = threadIdx.x; // 192 = 3 waves
  int c = t >> 6; int lane = t & 63;
  float acc = 0.f;
  const float* xr = x + (size_t)r*D;
  for (int d = lane; d < D; d += 64) acc += xr[d]*vel_w[d*3+c];
  for (int s = 32; s > 0; s >>= 1) acc += __shfl_down(acc, s);
  if (lane == 0) out[r*3+c] = acc + vel_b[c];
}

// ============================================================================
static void gemm(const float* A, int lda, const float* W, int ldw, const float* bias,
                 const float* res, float* C, int ldc, int M, int N, int K, int act,
                 const int* Mdev, hipStream_t s){
  dim3 g(N/64, (M+63)/64);
  k_gemm<<<g, 256, 0, s>>>(A, lda, W, ldw, bias, res, C, ldc, M, N, K, act, Mdev);
}

extern "C" void kernel_launch(void* const* d_in, const int* in_sizes, int n_in,
                              void* d_out, int out_size, void* d_ws, size_t ws_size,
                              hipStream_t stream){
  const float* x_t        = (const float*)d_in[0];
  const float* t_in       = (const float*)d_in[1];
  const float* coarse     = (const float*)d_in[2];
  const float* radar      = (const float*)d_in[3];
  const float* pc_w       = (const float*)d_in[4];
  const float* pc_b       = (const float*)d_in[5];
  const float* coarse_w   = (const float*)d_in[6];
  const float* coarse_b   = (const float*)d_in[7];
  const float* state_w    = (const float*)d_in[8];
  const float* state_b    = (const float*)d_in[9];
  const float* jid_emb    = (const float*)d_in[10];
  const float* dop_w1     = (const float*)d_in[11];
  const float* dop_b1     = (const float*)d_in[12];
  const float* dop_w2     = (const float*)d_in[13];
  const float* dop_b2     = (const float*)d_in[14];
  const float* time_w1    = (const float*)d_in[15];
  const float* time_b1    = (const float*)d_in[16];
  const float* time_w2    = (const float*)d_in[17];
  const float* time_b2    = (const float*)d_in[18];
  const float* mod_w1     = (const float*)d_in[19];
  const float* mod_b1     = (const float*)d_in[20];
  const float* mod_w2     = (const float*)d_in[21];
  const float* mod_b2     = (const float*)d_in[22];
  const float* diff_w     = (const float*)d_in[23];
  const float* diff_b     = (const float*)d_in[24];
  const float* vel_w      = (const float*)d_in[25];
  const float* vel_b      = (const float*)d_in[26];
  const float* sa_qkv_w   = (const float*)d_in[27];
  const float* sa_qkv_b   = (const float*)d_in[28];
  const float* sa_out_w   = (const float*)d_in[29];
  const float* sa_out_b   = (const float*)d_in[30];
  const float* ca_qkv_w   = (const float*)d_in[31];
  const float* ca_qkv_b   = (const float*)d_in[32];
  const float* ca_out_w   = (const float*)d_in[33];
  const float* ca_out_b   = (const float*)d_in[34];
  const float* ff1_w      = (const float*)d_in[35];
  const float* ff1_b      = (const float*)d_in[36];
  const float* ff2_w      = (const float*)d_in[37];
  const float* ff2_b      = (const float*)d_in[38];
  const float* ln1_s      = (const float*)d_in[39];
  const float* ln1_b      = (const float*)d_in[40];
  const float* ln2_s      = (const float*)d_in[41];
  const float* ln2_b      = (const float*)d_in[42];
  const float* ln3_s      = (const float*)d_in[43];
  const float* ln3_b      = (const float*)d_in[44];
  (void)in_sizes; (void)n_in; (void)out_size; (void)ws_size;

  const int R = NB*J; // 1728 rows

  // bump allocator over d_ws (256B aligned)
  char* wp = (char*)d_ws;
  auto alloc = [&](size_t bytes)->void*{
    void* r = (void*)wp;
    wp += (bytes + 255) & ~(size_t)255;
    return r;
  };
  float*        denom_sum = (float*)alloc(R*4);
  int*          rescue    = (int*)  alloc(R*4);
  int*          allm      = (int*)  alloc(R*4);
  unsigned int* bitmap    = (unsigned int*)alloc(NB*(NP/32)*4);
  int*          act_idx   = (int*)  alloc(NB*CAP*4);
  int*          act_cnt   = (int*)  alloc(NB*4);
  int*          act_off   = (int*)  alloc(NB*4);
  int*          act_total = (int*)  alloc(64);
  float* Gp       = (float*)alloc((size_t)NB*GCH*J*64*4);
  float* h_dop    = (float*)alloc((size_t)R*D*4);
  float* h_state  = (float*)alloc((size_t)R*D*4);
  float* h_coarse = (float*)alloc((size_t)R*D*4);
  float* hstruct  = (float*)alloc((size_t)R*D*4);
  float* xres     = (float*)alloc((size_t)R*D*4);
  float* hbuf     = (float*)alloc((size_t)R*D*4);
  float* attno    = (float*)alloc((size_t)R*D*4);
  float* qbuf     = (float*)alloc((size_t)R*D*4);
  float* th       = (float*)alloc((size_t)NB*D*4);
  float* h_time   = (float*)alloc((size_t)NB*D*4);
  float* mod1     = (float*)alloc((size_t)R*2*D*4);   // ffh aliases mod1+mod2
  float* mod2     = (float*)alloc((size_t)R*2*D*4);
  float* qkv      = (float*)alloc((size_t)R*3*D*4);   // hs2 aliases qkv
  float* mem_act  = (float*)alloc((size_t)NB*CAP*D*4);
  float* kv_act   = (float*)alloc((size_t)NB*CAP*2*D*4);
  float* ffh = mod1;       // (R,2048) = mod1(R,1024)+mod2(R,1024) contiguous
  float* hs2 = qkv;        // (R,1024) fits in qkv (R,1536)

  // ---- stage 0: masks / active set / h_dop ----
  hipMemsetAsync(bitmap, 0, NB*(NP/32)*4, stream);
  k_perj<<<R, 256, 0, stream>>>(x_t, radar, denom_sum, rescue, allm, bitmap);
  k_compact<<<NB, 64, 0, stream>>>(bitmap, act_idx, act_cnt);
  k_scan<<<1, 64, 0, stream>>>(act_cnt, act_off, act_total);
  k_gpart<<<dim3(NB, GCH), 256, 0, stream>>>(x_t, radar, dop_w1, dop_b1, Gp);
  k_hdop2<<<R, 64, 0, stream>>>(Gp, dop_w2, dop_b2, denom_sum, h_dop);

  // ---- stage 1: query build ----
  k_proj3<<<(R*D+255)/256, 256, 0, stream>>>(x_t, state_w, state_b, h_state, R);
  k_proj3<<<(R*D+255)/256, 256, 0, stream>>>(coarse, coarse_w, coarse_b, h_coarse, R);
  k_th<<<(NB*D+255)/256, 256, 0, stream>>>(t_in, time_w1, time_b1, th);
  gemm(th, D, time_w2, D, time_b2, nullptr, h_time, D, NB, D, D, 0, nullptr, stream);
  gemm(h_state, D, mod_w1, 2*D, mod_b1, nullptr, mod1, 2*D, R, 2*D, D, 1, nullptr, stream);
  gemm(mod1, 2*D, mod_w2, 2*D, mod_b2, nullptr, mod2, 2*D, R, 2*D, 2*D, 0, nullptr, stream);
  k_hs2<<<(R*2*D+255)/256, 256, 0, stream>>>(h_state, hs2);
  gemm(hs2, 2*D, diff_w, D, diff_b, nullptr, hstruct, D, R, D, 2*D, 0, nullptr, stream);
  k_query<<<(R*D+255)/256, 256, 0, stream>>>(h_coarse, h_time, h_dop, h_state, hstruct,
                                             jid_emb, mod2, xres);
  k_memact<<<NB*CAP, 128, 0, stream>>>(x_t, radar, pc_w, pc_b, act_idx, act_cnt, act_off, mem_act);

  // ---- stage 2: transformer layers ----
  for (int l = 0; l < NLAYER; ++l){
    k_ln<<<R, 256, 0, stream>>>(xres, ln1_s + l*D, ln1_b + l*D, hbuf);
    gemm(hbuf, D, sa_qkv_w + (size_t)l*D*3*D, 3*D, sa_qkv_b + l*3*D, nullptr,
         qkv, 3*D, R, 3*D, D, 0, nullptr, stream);
    k_selfattn<<<NB*H, 256, 0, stream>>>(qkv, attno);
    gemm(attno, D, sa_out_w + (size_t)l*D*D, D, sa_out_b + l*D, xres,
         xres, D, R, D, D, 0, nullptr, stream);

    k_ln<<<R, 256, 0, stream>>>(xres, ln2_s + l*D, ln2_b + l*D, hbuf);
    gemm(hbuf, D, ca_qkv_w + (size_t)l*D*3*D, 3*D, ca_qkv_b + l*3*D, nullptr,
         qbuf, D, R, D, D, 0, nullptr, stream);
    gemm(mem_act, D, ca_qkv_w + (size_t)l*D*3*D + D, 3*D, ca_qkv_b + l*3*D + D, nullptr,
         kv_act, 2*D, NB*CAP, 2*D, D, 0, act_total, stream);
    k_crossattn<<<NB*H, 256, 0, stream>>>(qbuf, kv_act, x_t, radar, act_idx, act_cnt,
                                          act_off, rescue, allm, attno);
    gemm(attno, D, ca_out_w + (size_t)l*D*D, D, ca_out_b + l*D, xres,
         xres, D, R, D, D, 0, nullptr, stream);

    k_ln<<<R, 256, 0, stream>>>(xres, ln3_s + l*D, ln3_b + l*D, hbuf);
    gemm(hbuf, D, ff1_w + (size_t)l*D*DFF, DFF, ff1_b + l*DFF, nullptr,
         ffh, DFF, R, DFF, D, 2, nullptr, stream);
    gemm(ffh, DFF, ff2_w + (size_t)l*DFF*D, D, ff2_b + l*D, xres,
         xres, D, R, D, DFF, 0, nullptr, stream);
  }

  k_vel<<<R, 192, 0, stream>>>(xres, vel_w, vel_b, (float*)d_out);
}